// Round 1
// baseline (567.286 us; speedup 1.0000x reference)
//
#include <hip/hip_runtime.h>
#include <hip/hip_bf16.h>
#include <math.h>

typedef __attribute__((ext_vector_type(8))) short short8;
typedef __attribute__((ext_vector_type(4))) short sv4;
typedef __attribute__((ext_vector_type(4))) float f32x4;

#define S_LEN 2048
#define NH 16
#define DMODEL 1024
#define DKH 64
// log2(e)/8 : scores tracked in exp2-units so exp() is a single v_exp_f32
#define SC 0.18033688011112042f

static __device__ __forceinline__ short f2bf(float f) {
  unsigned u = __builtin_bit_cast(unsigned, f);
  unsigned r = (u + 0x7fffu + ((u >> 16) & 1u)) >> 16;
  return (short)r;
}

static __device__ __forceinline__ void gld16(const void* g, void* l) {
  __builtin_amdgcn_global_load_lds((const __attribute__((address_space(1))) void*)g,
                                   (__attribute__((address_space(3))) void*)l, 16, 0, 0);
}

static __device__ __forceinline__ f32x4 mfma_bf16(short8 a, short8 b, f32x4 c) {
  return __builtin_amdgcn_mfma_f32_16x16x32_bf16(a, b, c, 0, 0, 0);
}

// ---------------- cast fp32 -> bf16 for q/k/v inputs ----------------
__global__ __launch_bounds__(256) void cast3_kernel(const float* __restrict__ q, const float* __restrict__ k,
                                                    const float* __restrict__ v,
                                                    short* __restrict__ oq, short* __restrict__ ok_,
                                                    short* __restrict__ ov) {
  const float* in = blockIdx.y == 0 ? q : (blockIdx.y == 1 ? k : v);
  short* out = blockIdx.y == 0 ? oq : (blockIdx.y == 1 ? ok_ : ov);
  int i = blockIdx.x * 256 + threadIdx.x;
  float4 f = ((const float4*)in)[i];
  sv4 o = {f2bf(f.x), f2bf(f.y), f2bf(f.z), f2bf(f.w)};
  ((sv4*)out)[i] = o;
}

// ---------------- transpose-cast weights: out[n][k] = bf16(in[k][n]) ----------------
__global__ __launch_bounds__(256) void wtrans_kernel(const float* __restrict__ w0, const float* __restrict__ w1,
                                                     const float* __restrict__ w2, const float* __restrict__ w3,
                                                     short* __restrict__ o0, short* __restrict__ o1,
                                                     short* __restrict__ o2, short* __restrict__ o3) {
  const float* in = blockIdx.z == 0 ? w0 : blockIdx.z == 1 ? w1 : blockIdx.z == 2 ? w2 : w3;
  short* out = blockIdx.z == 0 ? o0 : blockIdx.z == 1 ? o1 : blockIdx.z == 2 ? o2 : o3;
  __shared__ float t[64][65];
  int tx = threadIdx.x & 63, ty = threadIdx.x >> 6;
  int bx = blockIdx.x * 64, by = blockIdx.y * 64;  // bx: n, by: k
#pragma unroll
  for (int i = 0; i < 16; ++i)
    t[ty + i * 4][tx] = in[(by + ty + i * 4) * DMODEL + bx + tx];
  __syncthreads();
#pragma unroll
  for (int i = 0; i < 16; ++i)
    out[(bx + ty + i * 4) * DMODEL + by + tx] = f2bf(t[tx][ty + i * 4]);
}

// ---------------- projection GEMM: C[m,n] = A[m,:] . W[n,:] + bias[n] ----------------
// MODE 0: out bf16 [B,H,S,DK] (Q,K)   MODE 1: out bf16 [B,H,DK,S] (V^T)   MODE 3: out fp32 [M,N]
template <int MODE>
__global__ __launch_bounds__(256) void proj_kernel(const short* __restrict__ A, const short* __restrict__ W,
                                                   const float* __restrict__ bias, void* __restrict__ outp) {
  const int tid = threadIdx.x;
  const int wid = tid >> 6, lane = tid & 63;
  const int g = lane >> 4, li = lane & 15;
  const int wm = (wid >> 1) * 64, wn = (wid & 1) * 64;
  const int bn = blockIdx.x * 128, bm = blockIdx.y * 128;

  __shared__ __align__(16) short As[4096];
  __shared__ __align__(16) short Bs[4096];
  __shared__ __align__(16) short T[MODE == 1 ? 128 * 136 : 8];

  f32x4 acc[4][4];
#pragma unroll
  for (int m = 0; m < 4; ++m)
#pragma unroll
    for (int n = 0; n < 4; ++n) acc[m][n] = (f32x4){0.f, 0.f, 0.f, 0.f};

  for (int ks = 0; ks < 32; ++ks) {
    const int k0 = ks * 32;
    __syncthreads();
#pragma unroll
    for (int i = 0; i < 2; ++i) {
      int slot = i * 256 + tid;
      int r = slot >> 2, pos = slot & 3;
      int lch = pos ^ ((r >> 1) & 3);
      gld16(A + (size_t)(bm + r) * DMODEL + k0 + lch * 8, As + slot * 8);
      gld16(W + (size_t)(bn + r) * DMODEL + k0 + lch * 8, Bs + slot * 8);
    }
    __syncthreads();
    short8 av[4], bv[4];
#pragma unroll
    for (int m = 0; m < 4; ++m) {
      int r = wm + m * 16 + li;
      av[m] = *(const short8*)(As + r * 32 + (g ^ ((r >> 1) & 3)) * 8);
    }
#pragma unroll
    for (int n = 0; n < 4; ++n) {
      int r = wn + n * 16 + li;
      bv[n] = *(const short8*)(Bs + r * 32 + (g ^ ((r >> 1) & 3)) * 8);
    }
#pragma unroll
    for (int m = 0; m < 4; ++m)
#pragma unroll
      for (int n = 0; n < 4; ++n) acc[m][n] = mfma_bf16(av[m], bv[n], acc[m][n]);
  }

  if (MODE == 0) {
    short* out = (short*)outp;
#pragma unroll
    for (int n = 0; n < 4; ++n) {
      int col = bn + wn + n * 16 + li;
      float bb = bias[col];
      int h = col >> 6, dk = col & 63;
#pragma unroll
      for (int m = 0; m < 4; ++m)
#pragma unroll
        for (int j = 0; j < 4; ++j) {
          int row = bm + wm + m * 16 + g * 4 + j;
          int b_ = row >> 11, s_ = row & 2047;
          out[(size_t)((b_ * NH + h) * S_LEN + s_) * DKH + dk] = f2bf(acc[m][n][j] + bb);
        }
    }
  } else if (MODE == 3) {
    float* out = (float*)outp;
#pragma unroll
    for (int n = 0; n < 4; ++n) {
      int col = bn + wn + n * 16 + li;
      float bb = bias[col];
#pragma unroll
      for (int m = 0; m < 4; ++m)
#pragma unroll
        for (int j = 0; j < 4; ++j) {
          int row = bm + wm + m * 16 + g * 4 + j;
          out[(size_t)row * DMODEL + col] = acc[m][n][j] + bb;
        }
    }
  } else {  // MODE 1: V^T via LDS transpose, coalesced along s
    short* out = (short*)outp;
#pragma unroll
    for (int n = 0; n < 4; ++n) {
      int colL = wn + n * 16 + li;
      float bb = bias[bn + colL];
#pragma unroll
      for (int m = 0; m < 4; ++m)
#pragma unroll
        for (int j = 0; j < 4; ++j) {
          int rowL = wm + m * 16 + g * 4 + j;
          T[colL * 136 + rowL] = f2bf(acc[m][n][j] + bb);
        }
    }
    __syncthreads();
    int r = tid >> 1, half = tid & 1;
    int nglob = bn + r;
    int h = nglob >> 6, dk = nglob & 63;
    int b_ = bm >> 11;
    int s0 = (bm & 2047) + half * 64;
    short* op = out + (size_t)((b_ * NH + h) * DKH + dk) * S_LEN + s0;
    const short* tp = T + r * 136 + half * 64;
#pragma unroll
    for (int i = 0; i < 8; ++i) *(short8*)(op + i * 8) = *(const short8*)(tp + i * 8);
  }
}

// ---------------- attention pass 1: row max + sumexp (exp2 units) ----------------
__global__ __launch_bounds__(256) void attn_pass1(const short* __restrict__ Qh, const short* __restrict__ Kh,
                                                  const int* __restrict__ mask,
                                                  float* __restrict__ mrow, float* __restrict__ lrow) {
  const int tid = threadIdx.x;
  const int wid = tid >> 6, lane = tid & 63;
  const int g = lane >> 4, li = lane & 15;
  const int h = blockIdx.y, b = blockIdx.z;
  const int bh = b * NH + h;
  const int q0 = blockIdx.x * 64 + wid * 16;

  const short* qptr = Qh + (size_t)(bh * S_LEN + q0 + li) * DKH;
  const short8 aq0 = *(const short8*)(qptr + g * 8);
  const short8 aq1 = *(const short8*)(qptr + 32 + g * 8);

  __shared__ __align__(16) short Ks[4096];

  float mL[4] = {-INFINITY, -INFINITY, -INFINITY, -INFINITY};
  float lL[4] = {0.f, 0.f, 0.f, 0.f};

  for (int kt = 0; kt < 32; ++kt) {
    const int k0 = kt * 64;
    __syncthreads();
#pragma unroll
    for (int i = 0; i < 2; ++i) {
      int slot = i * 256 + tid;
      int r = slot >> 3, pos = slot & 7;
      int lch = pos ^ (r & 7);
      gld16(Kh + (size_t)(bh * S_LEN + k0 + r) * DKH + lch * 8, Ks + slot * 8);
    }
    __syncthreads();

    f32x4 acc[4];
#pragma unroll
    for (int nf = 0; nf < 4; ++nf) {
      acc[nf] = (f32x4){0.f, 0.f, 0.f, 0.f};
      int rB = nf * 16 + li;
      const short8 b0 = *(const short8*)(Ks + rB * 64 + ((0 + g) ^ (rB & 7)) * 8);
      const short8 b1 = *(const short8*)(Ks + rB * 64 + ((4 + g) ^ (rB & 7)) * 8);
      acc[nf] = mfma_bf16(aq0, b0, acc[nf]);
      acc[nf] = mfma_bf16(aq1, b1, acc[nf]);
    }

#pragma unroll
    for (int j = 0; j < 4; ++j) {
      const int qrow = q0 + g * 4 + j;
      const int* mp = mask + (size_t)(b * S_LEN + qrow) * S_LEN + k0 + li;
      float s0 = mp[0] ? acc[0][j] * SC : -INFINITY;
      float s1 = mp[16] ? acc[1][j] * SC : -INFINITY;
      float s2 = mp[32] ? acc[2][j] * SC : -INFINITY;
      float s3 = mp[48] ? acc[3][j] * SC : -INFINITY;
      float nm = fmaxf(fmaxf(s0, s1), fmaxf(s2, s3));
      nm = fmaxf(nm, mL[j]);
      if (nm > -INFINITY) {
        float sum = exp2f(s0 - nm) + exp2f(s1 - nm) + exp2f(s2 - nm) + exp2f(s3 - nm);
        lL[j] = lL[j] * exp2f(mL[j] - nm) + sum;
        mL[j] = nm;
      }
    }
  }

#pragma unroll
  for (int d = 1; d < 16; d <<= 1) {
#pragma unroll
    for (int j = 0; j < 4; ++j) {
      float om = __shfl_xor(mL[j], d);
      float ol = __shfl_xor(lL[j], d);
      float nm = fmaxf(mL[j], om);
      float t0 = (mL[j] > -INFINITY) ? lL[j] * exp2f(mL[j] - nm) : 0.f;
      float t1 = (om > -INFINITY) ? ol * exp2f(om - nm) : 0.f;
      mL[j] = nm;
      lL[j] = t0 + t1;
    }
  }
  if (li == 0) {
#pragma unroll
    for (int j = 0; j < 4; ++j) {
      int q = q0 + g * 4 + j;
      mrow[bh * S_LEN + q] = mL[j];
      lrow[bh * S_LEN + q] = lL[j];
    }
  }
}

// ---------------- attention pass 2: p_attn write + PV ----------------
__global__ __launch_bounds__(256) void attn_pass2(const short* __restrict__ Qh, const short* __restrict__ Kh,
                                                  const short* __restrict__ Vt, const int* __restrict__ mask,
                                                  const float* __restrict__ mrow, const float* __restrict__ lrow,
                                                  float* __restrict__ pattn, short* __restrict__ xout) {
  const int tid = threadIdx.x;
  const int wid = tid >> 6, lane = tid & 63;
  const int g = lane >> 4, li = lane & 15;
  const int h = blockIdx.y, b = blockIdx.z;
  const int bh = b * NH + h;
  const int q0 = blockIdx.x * 64 + wid * 16;

  const short* qptr = Qh + (size_t)(bh * S_LEN + q0 + li) * DKH;
  const short8 aq0 = *(const short8*)(qptr + g * 8);
  const short8 aq1 = *(const short8*)(qptr + 32 + g * 8);

  __shared__ __align__(16) short Ks[4096];
  __shared__ __align__(16) short Vs[4096];
  __shared__ __align__(16) short Ps[4096];

  float m2[4], linv[4];
#pragma unroll
  for (int j = 0; j < 4; ++j) {
    int q = q0 + g * 4 + j;
    m2[j] = mrow[bh * S_LEN + q];
    linv[j] = 1.f / lrow[bh * S_LEN + q];
  }

  f32x4 accx[4];
#pragma unroll
  for (int nf = 0; nf < 4; ++nf) accx[nf] = (f32x4){0.f, 0.f, 0.f, 0.f};

  for (int kt = 0; kt < 32; ++kt) {
    const int k0 = kt * 64;
    __syncthreads();
#pragma unroll
    for (int i = 0; i < 2; ++i) {
      int slot = i * 256 + tid;
      int r = slot >> 3, pos = slot & 7;
      int lch = pos ^ (r & 7);
      gld16(Kh + (size_t)(bh * S_LEN + k0 + r) * DKH + lch * 8, Ks + slot * 8);
      gld16(Vt + (size_t)(bh * DKH + r) * S_LEN + k0 + lch * 8, Vs + slot * 8);
    }
    __syncthreads();

    f32x4 acc[4];
#pragma unroll
    for (int nf = 0; nf < 4; ++nf) {
      acc[nf] = (f32x4){0.f, 0.f, 0.f, 0.f};
      int rB = nf * 16 + li;
      const short8 b0 = *(const short8*)(Ks + rB * 64 + ((0 + g) ^ (rB & 7)) * 8);
      const short8 b1 = *(const short8*)(Ks + rB * 64 + ((4 + g) ^ (rB & 7)) * 8);
      acc[nf] = mfma_bf16(aq0, b0, acc[nf]);
      acc[nf] = mfma_bf16(aq1, b1, acc[nf]);
    }

#pragma unroll
    for (int j = 0; j < 4; ++j) {
      const int qrow = q0 + g * 4 + j;
      const int* mp = mask + (size_t)(b * S_LEN + qrow) * S_LEN + k0 + li;
      float* pp = pattn + (size_t)(bh * S_LEN + qrow) * S_LEN + k0 + li;
      const int row = g * 4 + j;
#pragma unroll
      for (int nf = 0; nf < 4; ++nf) {
        float s = mp[nf * 16] ? acc[nf][j] * SC : -INFINITY;
        float p = exp2f(s - m2[j]) * linv[j];
        pp[nf * 16] = p;
        int col = nf * 16 + li;
        int sidx = row * 64 + (((col >> 3) ^ (row & 7)) * 8) + (col & 7);
        Ps[wid * 1024 + sidx] = f2bf(p);
      }
    }

    const short8 pa0 = *(const short8*)(Ps + wid * 1024 + li * 64 + ((0 + g) ^ (li & 7)) * 8);
    const short8 pa1 = *(const short8*)(Ps + wid * 1024 + li * 64 + ((4 + g) ^ (li & 7)) * 8);

#pragma unroll
    for (int nf = 0; nf < 4; ++nf) {
      int rv = nf * 16 + li;
      const short8 v0 = *(const short8*)(Vs + rv * 64 + ((0 + g) ^ (rv & 7)) * 8);
      const short8 v1 = *(const short8*)(Vs + rv * 64 + ((4 + g) ^ (rv & 7)) * 8);
      accx[nf] = mfma_bf16(pa0, v0, accx[nf]);
      accx[nf] = mfma_bf16(pa1, v1, accx[nf]);
    }
  }

#pragma unroll
  for (int nf = 0; nf < 4; ++nf) {
    int d = nf * 16 + li;
#pragma unroll
    for (int j = 0; j < 4; ++j) {
      int q = q0 + g * 4 + j;
      xout[(size_t)(b * S_LEN + q) * DMODEL + h * DKH + d] = f2bf(accx[nf][j]);
    }
  }
}

extern "C" void kernel_launch(void* const* d_in, const int* in_sizes, int n_in,
                              void* d_out, int out_size, void* d_ws, size_t ws_size,
                              hipStream_t stream) {
  (void)in_sizes; (void)n_in; (void)out_size; (void)ws_size;
  const float* query = (const float*)d_in[0];
  const float* key = (const float*)d_in[1];
  const float* value = (const float*)d_in[2];
  const int* mask = (const int*)d_in[3];
  const float* wq = (const float*)d_in[4];
  const float* bq = (const float*)d_in[5];
  const float* wk = (const float*)d_in[6];
  const float* bk = (const float*)d_in[7];
  const float* wv = (const float*)d_in[8];
  const float* bv = (const float*)d_in[9];
  const float* wo = (const float*)d_in[10];
  const float* bo = (const float*)d_in[11];

  char* ws = (char*)d_ws;
  const size_t MB = 1u << 20;
  short* qb = (short*)(ws + 0 * MB);
  short* kb = (short*)(ws + 8 * MB);
  short* vb = (short*)(ws + 16 * MB);
  short* wqT = (short*)(ws + 24 * MB);
  short* wkT = (short*)(ws + 26 * MB);
  short* wvT = (short*)(ws + 28 * MB);
  short* woT = (short*)(ws + 30 * MB);
  short* Qh = (short*)(ws + 32 * MB);
  short* Kh = (short*)(ws + 40 * MB);
  short* Vt = (short*)(ws + 48 * MB);
  float* mrow = (float*)(ws + 56 * MB);
  float* lrow = (float*)(ws + 56 * MB + 256 * 1024);
  short* xb = (short*)(ws + 57 * MB);

  float* out_x = (float*)d_out;
  float* out_p = (float*)d_out + 4194304;

  cast3_kernel<<<dim3(4096, 3), 256, 0, stream>>>(query, key, value, qb, kb, vb);
  wtrans_kernel<<<dim3(16, 16, 4), 256, 0, stream>>>(wq, wk, wv, wo, wqT, wkT, wvT, woT);
  proj_kernel<0><<<dim3(8, 32), 256, 0, stream>>>(qb, wqT, bq, Qh);
  proj_kernel<0><<<dim3(8, 32), 256, 0, stream>>>(kb, wkT, bk, Kh);
  proj_kernel<1><<<dim3(8, 32), 256, 0, stream>>>(vb, wvT, bv, Vt);
  attn_pass1<<<dim3(32, 16, 2), 256, 0, stream>>>(Qh, Kh, mask, mrow, lrow);
  attn_pass2<<<dim3(32, 16, 2), 256, 0, stream>>>(Qh, Kh, Vt, mask, mrow, lrow, out_p, xb);
  proj_kernel<3><<<dim3(8, 32), 256, 0, stream>>>(xb, woT, bo, out_x);
}

// Round 2
// 389.030 us; speedup vs baseline: 1.4582x; 1.4582x over previous
//
#include <hip/hip_runtime.h>
#include <hip/hip_bf16.h>
#include <math.h>

typedef __attribute__((ext_vector_type(8))) short short8;
typedef __attribute__((ext_vector_type(4))) short sv4;
typedef __attribute__((ext_vector_type(4))) float f32x4;

#define S_LEN 2048
#define NH 16
#define DMODEL 1024
#define DKH 64
// log2(e)/8 : scores tracked in exp2-units so exp() is a single v_exp_f32
#define SC 0.18033688011112042f

static __device__ __forceinline__ short f2bf(float f) {
  unsigned u = __builtin_bit_cast(unsigned, f);
  unsigned r = (u + 0x7fffu + ((u >> 16) & 1u)) >> 16;
  return (short)r;
}

static __device__ __forceinline__ float bf2f(short s) {
  return __builtin_bit_cast(float, ((unsigned)(unsigned short)s) << 16);
}

static __device__ __forceinline__ float e2(float x) { return __builtin_amdgcn_exp2f(x); }

static __device__ __forceinline__ void gld16(const void* g, void* l) {
  __builtin_amdgcn_global_load_lds((const __attribute__((address_space(1))) void*)g,
                                   (__attribute__((address_space(3))) void*)l, 16, 0, 0);
}

static __device__ __forceinline__ f32x4 mfma_bf16(short8 a, short8 b, f32x4 c) {
  return __builtin_amdgcn_mfma_f32_16x16x32_bf16(a, b, c, 0, 0, 0);
}

// ---------------- cast fp32 -> bf16 for q/k/v inputs ----------------
__global__ __launch_bounds__(256) void cast3_kernel(const float* __restrict__ q, const float* __restrict__ k,
                                                    const float* __restrict__ v,
                                                    short* __restrict__ oq, short* __restrict__ ok_,
                                                    short* __restrict__ ov) {
  const float* in = blockIdx.y == 0 ? q : (blockIdx.y == 1 ? k : v);
  short* out = blockIdx.y == 0 ? oq : (blockIdx.y == 1 ? ok_ : ov);
  int i = blockIdx.x * 256 + threadIdx.x;
  float4 f = ((const float4*)in)[i];
  sv4 o = {f2bf(f.x), f2bf(f.y), f2bf(f.z), f2bf(f.w)};
  ((sv4*)out)[i] = o;
}

// ---------------- bit-pack mask rows: maskb[row][k/64] u64 ----------------
__global__ __launch_bounds__(256) void maskpack_kernel(const int* __restrict__ mask,
                                                       unsigned long long* __restrict__ mb) {
  int row = blockIdx.x;  // b*S + q
  int w = threadIdx.x >> 6, lane = threadIdx.x & 63;
  const int* mp = mask + (size_t)row * S_LEN;
#pragma unroll
  for (int c = 0; c < 8; ++c) {
    int ci = w * 8 + c;
    unsigned long long bits = __ballot(mp[ci * 64 + lane] != 0);
    if (lane == 0) mb[(size_t)row * 32 + ci] = bits;
  }
}

// ---------------- transpose-cast weights: out[n][k] = bf16(in[k][n]) ----------------
__global__ __launch_bounds__(256) void wtrans_kernel(const float* __restrict__ w0, const float* __restrict__ w1,
                                                     const float* __restrict__ w2, const float* __restrict__ w3,
                                                     short* __restrict__ o0, short* __restrict__ o1,
                                                     short* __restrict__ o2, short* __restrict__ o3) {
  const float* in = blockIdx.z == 0 ? w0 : blockIdx.z == 1 ? w1 : blockIdx.z == 2 ? w2 : w3;
  short* out = blockIdx.z == 0 ? o0 : blockIdx.z == 1 ? o1 : blockIdx.z == 2 ? o2 : o3;
  __shared__ float t[64][65];
  int tx = threadIdx.x & 63, ty = threadIdx.x >> 6;
  int bx = blockIdx.x * 64, by = blockIdx.y * 64;  // bx: n, by: k
#pragma unroll
  for (int i = 0; i < 16; ++i)
    t[ty + i * 4][tx] = in[(by + ty + i * 4) * DMODEL + bx + tx];
  __syncthreads();
#pragma unroll
  for (int i = 0; i < 16; ++i)
    out[(bx + ty + i * 4) * DMODEL + by + tx] = f2bf(t[tx][ty + i * 4]);
}

// ---------------- projection GEMM: C[m,n] = A[m,:] . W[n,:] + bias[n] ----------------
// MODE 0: out bf16 [B,H,S,DK] (Q,K)   MODE 1: out bf16 [B,H,DK,S] (V^T)   MODE 3: out fp32 [M,N]
template <int MODE>
__global__ __launch_bounds__(256) void proj_kernel(const short* __restrict__ A, const short* __restrict__ W,
                                                   const float* __restrict__ bias, void* __restrict__ outp) {
  const int tid = threadIdx.x;
  const int wid = tid >> 6, lane = tid & 63;
  const int g = lane >> 4, li = lane & 15;
  const int wm = (wid >> 1) * 64, wn = (wid & 1) * 64;
  const int bn = blockIdx.x * 128, bm = blockIdx.y * 128;

  __shared__ __align__(16) short As[4096];
  __shared__ __align__(16) short Bs[4096];
  __shared__ __align__(16) short T[MODE == 1 ? 128 * 136 : 8];

  f32x4 acc[4][4];
#pragma unroll
  for (int m = 0; m < 4; ++m)
#pragma unroll
    for (int n = 0; n < 4; ++n) acc[m][n] = (f32x4){0.f, 0.f, 0.f, 0.f};

  for (int ks = 0; ks < 32; ++ks) {
    const int k0 = ks * 32;
    __syncthreads();
#pragma unroll
    for (int i = 0; i < 2; ++i) {
      int slot = i * 256 + tid;
      int r = slot >> 2, pos = slot & 3;
      int lch = pos ^ ((r >> 1) & 3);
      gld16(A + (size_t)(bm + r) * DMODEL + k0 + lch * 8, As + slot * 8);
      gld16(W + (size_t)(bn + r) * DMODEL + k0 + lch * 8, Bs + slot * 8);
    }
    __syncthreads();
    short8 av[4], bv[4];
#pragma unroll
    for (int m = 0; m < 4; ++m) {
      int r = wm + m * 16 + li;
      av[m] = *(const short8*)(As + r * 32 + (g ^ ((r >> 1) & 3)) * 8);
    }
#pragma unroll
    for (int n = 0; n < 4; ++n) {
      int r = wn + n * 16 + li;
      bv[n] = *(const short8*)(Bs + r * 32 + (g ^ ((r >> 1) & 3)) * 8);
    }
#pragma unroll
    for (int m = 0; m < 4; ++m)
#pragma unroll
      for (int n = 0; n < 4; ++n) acc[m][n] = mfma_bf16(av[m], bv[n], acc[m][n]);
  }

  if (MODE == 0) {
    short* out = (short*)outp;
#pragma unroll
    for (int n = 0; n < 4; ++n) {
      int col = bn + wn + n * 16 + li;
      float bb = bias[col];
      int h = col >> 6, dk = col & 63;
#pragma unroll
      for (int m = 0; m < 4; ++m)
#pragma unroll
        for (int j = 0; j < 4; ++j) {
          int row = bm + wm + m * 16 + g * 4 + j;
          int b_ = row >> 11, s_ = row & 2047;
          out[(size_t)((b_ * NH + h) * S_LEN + s_) * DKH + dk] = f2bf(acc[m][n][j] + bb);
        }
    }
  } else if (MODE == 3) {
    float* out = (float*)outp;
#pragma unroll
    for (int n = 0; n < 4; ++n) {
      int col = bn + wn + n * 16 + li;
      float bb = bias[col];
#pragma unroll
      for (int m = 0; m < 4; ++m)
#pragma unroll
        for (int j = 0; j < 4; ++j) {
          int row = bm + wm + m * 16 + g * 4 + j;
          out[(size_t)row * DMODEL + col] = acc[m][n][j] + bb;
        }
    }
  } else {  // MODE 1: V^T via LDS transpose, coalesced along s
    short* out = (short*)outp;
#pragma unroll
    for (int n = 0; n < 4; ++n) {
      int colL = wn + n * 16 + li;
      float bb = bias[bn + colL];
#pragma unroll
      for (int m = 0; m < 4; ++m)
#pragma unroll
        for (int j = 0; j < 4; ++j) {
          int rowL = wm + m * 16 + g * 4 + j;
          T[colL * 136 + rowL] = f2bf(acc[m][n][j] + bb);
        }
    }
    __syncthreads();
    int r = tid >> 1, half = tid & 1;
    int nglob = bn + r;
    int h = nglob >> 6, dk = nglob & 63;
    int b_ = bm >> 11;
    int s0 = (bm & 2047) + half * 64;
    short* op = out + (size_t)((b_ * NH + h) * DKH + dk) * S_LEN + s0;
    const short* tp = T + r * 136 + half * 64;
#pragma unroll
    for (int i = 0; i < 8; ++i) *(short8*)(op + i * 8) = *(const short8*)(tp + i * 8);
  }
}

// ---------------- attention pass 1: row max + sumexp (exp2 units) ----------------
__global__ __launch_bounds__(256) void attn_pass1(const short* __restrict__ Qh, const short* __restrict__ Kh,
                                                  const unsigned long long* __restrict__ maskb,
                                                  float* __restrict__ mrow, float* __restrict__ lrow) {
  const int tid = threadIdx.x;
  const int wid = tid >> 6, lane = tid & 63;
  const int g = lane >> 4, li = lane & 15;
  const int h = blockIdx.y, b = blockIdx.z;
  const int bh = b * NH + h;
  const int q0 = blockIdx.x * 64 + wid * 16;

  const short* qptr = Qh + (size_t)(bh * S_LEN + q0 + li) * DKH;
  const short8 aq0 = *(const short8*)(qptr + g * 8);
  const short8 aq1 = *(const short8*)(qptr + 32 + g * 8);

  __shared__ __align__(16) short Ks[4096];

  float mL[4] = {-INFINITY, -INFINITY, -INFINITY, -INFINITY};
  float lL[4] = {0.f, 0.f, 0.f, 0.f};

  for (int kt = 0; kt < 32; ++kt) {
    const int k0 = kt * 64;
    __syncthreads();
#pragma unroll
    for (int i = 0; i < 2; ++i) {
      int slot = i * 256 + tid;
      int r = slot >> 3, pos = slot & 7;
      int lch = pos ^ (r & 7);
      gld16(Kh + (size_t)(bh * S_LEN + k0 + r) * DKH + lch * 8, Ks + slot * 8);
    }
    __syncthreads();

    f32x4 acc[4];
#pragma unroll
    for (int nf = 0; nf < 4; ++nf) {
      acc[nf] = (f32x4){0.f, 0.f, 0.f, 0.f};
      int rB = nf * 16 + li;
      const short8 b0 = *(const short8*)(Ks + rB * 64 + ((0 + g) ^ (rB & 7)) * 8);
      const short8 b1 = *(const short8*)(Ks + rB * 64 + ((4 + g) ^ (rB & 7)) * 8);
      acc[nf] = mfma_bf16(aq0, b0, acc[nf]);
      acc[nf] = mfma_bf16(aq1, b1, acc[nf]);
    }

#pragma unroll
    for (int j = 0; j < 4; ++j) {
      const int qrow = q0 + g * 4 + j;
      unsigned long long mb = maskb[(size_t)(b * S_LEN + qrow) * 32 + kt];
      float s0 = acc[0][j] * SC;
      float s1 = acc[1][j] * SC;
      float s2 = acc[2][j] * SC;
      float s3 = acc[3][j] * SC;
      if (mb != ~0ull) {
        if (!((mb >> li) & 1)) s0 = -INFINITY;
        if (!((mb >> (16 + li)) & 1)) s1 = -INFINITY;
        if (!((mb >> (32 + li)) & 1)) s2 = -INFINITY;
        if (!((mb >> (48 + li)) & 1)) s3 = -INFINITY;
      }
      float nm = fmaxf(fmaxf(s0, s1), fmaxf(s2, s3));
      nm = fmaxf(nm, mL[j]);
      if (nm > -INFINITY) {
        float sum = e2(s0 - nm) + e2(s1 - nm) + e2(s2 - nm) + e2(s3 - nm);
        lL[j] = lL[j] * e2(mL[j] - nm) + sum;
        mL[j] = nm;
      }
    }
  }

#pragma unroll
  for (int d = 1; d < 16; d <<= 1) {
#pragma unroll
    for (int j = 0; j < 4; ++j) {
      float om = __shfl_xor(mL[j], d);
      float ol = __shfl_xor(lL[j], d);
      float nm = fmaxf(mL[j], om);
      float t0 = (mL[j] > -INFINITY) ? lL[j] * e2(mL[j] - nm) : 0.f;
      float t1 = (om > -INFINITY) ? ol * e2(om - nm) : 0.f;
      mL[j] = nm;
      lL[j] = t0 + t1;
    }
  }
  if (li == 0) {
#pragma unroll
    for (int j = 0; j < 4; ++j) {
      int q = q0 + g * 4 + j;
      mrow[bh * S_LEN + q] = mL[j];
      lrow[bh * S_LEN + q] = lL[j];
    }
  }
}

// ---------------- attention pass 2: p_attn write + PV ----------------
__global__ __launch_bounds__(256) void attn_pass2(const short* __restrict__ Qh, const short* __restrict__ Kh,
                                                  const short* __restrict__ Vt,
                                                  const unsigned long long* __restrict__ maskb,
                                                  const float* __restrict__ mrow, const float* __restrict__ lrow,
                                                  float* __restrict__ pattn, short* __restrict__ xout) {
  const int tid = threadIdx.x;
  const int wid = tid >> 6, lane = tid & 63;
  const int g = lane >> 4, li = lane & 15;
  const int h = blockIdx.y, b = blockIdx.z;
  const int bh = b * NH + h;
  const int q0 = blockIdx.x * 64 + wid * 16;

  const short* qptr = Qh + (size_t)(bh * S_LEN + q0 + li) * DKH;
  const short8 aq0 = *(const short8*)(qptr + g * 8);
  const short8 aq1 = *(const short8*)(qptr + 32 + g * 8);

  __shared__ __align__(16) short Ks[4096];
  __shared__ __align__(16) short Vs[4096];
  __shared__ __align__(16) short Ps[4096];

  float m2[4], linv[4];
#pragma unroll
  for (int j = 0; j < 4; ++j) {
    int q = q0 + g * 4 + j;
    m2[j] = mrow[bh * S_LEN + q];
    linv[j] = 1.f / lrow[bh * S_LEN + q];
  }

  f32x4 accx[4];
#pragma unroll
  for (int nf = 0; nf < 4; ++nf) accx[nf] = (f32x4){0.f, 0.f, 0.f, 0.f};

  for (int kt = 0; kt < 32; ++kt) {
    const int k0 = kt * 64;
    __syncthreads();
#pragma unroll
    for (int i = 0; i < 2; ++i) {
      int slot = i * 256 + tid;
      int r = slot >> 3, pos = slot & 7;
      int lch = pos ^ (r & 7);
      gld16(Kh + (size_t)(bh * S_LEN + k0 + r) * DKH + lch * 8, Ks + slot * 8);
      gld16(Vt + (size_t)(bh * DKH + r) * S_LEN + k0 + lch * 8, Vs + slot * 8);
    }
    __syncthreads();

    f32x4 acc[4];
#pragma unroll
    for (int nf = 0; nf < 4; ++nf) {
      acc[nf] = (f32x4){0.f, 0.f, 0.f, 0.f};
      int rB = nf * 16 + li;
      const short8 b0 = *(const short8*)(Ks + rB * 64 + ((0 + g) ^ (rB & 7)) * 8);
      const short8 b1 = *(const short8*)(Ks + rB * 64 + ((4 + g) ^ (rB & 7)) * 8);
      acc[nf] = mfma_bf16(aq0, b0, acc[nf]);
      acc[nf] = mfma_bf16(aq1, b1, acc[nf]);
    }

    // softmax -> per-wave bf16 P tile in LDS (swizzled)
#pragma unroll
    for (int j = 0; j < 4; ++j) {
      const int qrow = q0 + g * 4 + j;
      unsigned long long mb = maskb[(size_t)(b * S_LEN + qrow) * 32 + kt];
      bool full = (mb == ~0ull);
      const int row = g * 4 + j;
#pragma unroll
      for (int nf = 0; nf < 4; ++nf) {
        float s = acc[nf][j] * SC;
        if (!full && !((mb >> (nf * 16 + li)) & 1)) s = -INFINITY;
        float p = e2(s - m2[j]) * linv[j];
        int col = nf * 16 + li;
        int sidx = row * 64 + (((col >> 3) ^ (row & 7)) * 8) + (col & 7);
        Ps[wid * 1024 + sidx] = f2bf(p);
      }
    }

    // PV
    const short8 pa0 = *(const short8*)(Ps + wid * 1024 + li * 64 + ((0 + g) ^ (li & 7)) * 8);
    const short8 pa1 = *(const short8*)(Ps + wid * 1024 + li * 64 + ((4 + g) ^ (li & 7)) * 8);

#pragma unroll
    for (int nf = 0; nf < 4; ++nf) {
      int rv = nf * 16 + li;
      const short8 v0 = *(const short8*)(Vs + rv * 64 + ((0 + g) ^ (rv & 7)) * 8);
      const short8 v1 = *(const short8*)(Vs + rv * 64 + ((4 + g) ^ (rv & 7)) * 8);
      accx[nf] = mfma_bf16(pa0, v0, accx[nf]);
      accx[nf] = mfma_bf16(pa1, v1, accx[nf]);
    }

    // cooperative vectorized p_attn write: each store instr covers 4 full 256B rows
    {
      const int rg = lane >> 4;   // row within 4-row group
      const int cp = lane & 15;   // 4-float col group
      const int c = cp * 4;
#pragma unroll
      for (int s = 0; s < 4; ++s) {
        int r = s * 4 + rg;
        int chunk = (c >> 3) ^ (r & 7);
        sv4 pv4 = *(const sv4*)(Ps + wid * 1024 + r * 64 + chunk * 8 + (c & 7));
        f32x4 w4;
        w4[0] = bf2f(pv4[0]);
        w4[1] = bf2f(pv4[1]);
        w4[2] = bf2f(pv4[2]);
        w4[3] = bf2f(pv4[3]);
        *(f32x4*)(pattn + (size_t)(bh * S_LEN + q0 + r) * S_LEN + k0 + c) = w4;
      }
    }
  }

#pragma unroll
  for (int nf = 0; nf < 4; ++nf) {
    int d = nf * 16 + li;
#pragma unroll
    for (int j = 0; j < 4; ++j) {
      int q = q0 + g * 4 + j;
      xout[(size_t)(b * S_LEN + q) * DMODEL + h * DKH + d] = f2bf(accx[nf][j]);
    }
  }
}

extern "C" void kernel_launch(void* const* d_in, const int* in_sizes, int n_in,
                              void* d_out, int out_size, void* d_ws, size_t ws_size,
                              hipStream_t stream) {
  (void)in_sizes; (void)n_in; (void)out_size; (void)ws_size;
  const float* query = (const float*)d_in[0];
  const float* key = (const float*)d_in[1];
  const float* value = (const float*)d_in[2];
  const int* mask = (const int*)d_in[3];
  const float* wq = (const float*)d_in[4];
  const float* bq = (const float*)d_in[5];
  const float* wk = (const float*)d_in[6];
  const float* bk = (const float*)d_in[7];
  const float* wv = (const float*)d_in[8];
  const float* bv = (const float*)d_in[9];
  const float* wo = (const float*)d_in[10];
  const float* bo = (const float*)d_in[11];

  char* ws = (char*)d_ws;
  const size_t MB = 1u << 20;
  short* qb = (short*)(ws + 0 * MB);
  short* kb = (short*)(ws + 8 * MB);
  short* vb = (short*)(ws + 16 * MB);
  short* wqT = (short*)(ws + 24 * MB);
  short* wkT = (short*)(ws + 26 * MB);
  short* wvT = (short*)(ws + 28 * MB);
  short* woT = (short*)(ws + 30 * MB);
  short* Qh = (short*)(ws + 32 * MB);
  short* Kh = (short*)(ws + 40 * MB);
  short* Vt = (short*)(ws + 48 * MB);
  float* mrow = (float*)(ws + 56 * MB);
  float* lrow = (float*)(ws + 56 * MB + 256 * 1024);
  short* xb = (short*)(ws + 57 * MB);
  // maskb reuses qb's region (qb is dead after the Q projection; maskpack is
  // launched after proj_kernel<0>(qb,...) in stream order)
  unsigned long long* maskb = (unsigned long long*)(ws + 0 * MB);

  float* out_x = (float*)d_out;
  float* out_p = (float*)d_out + 4194304;

  cast3_kernel<<<dim3(4096, 3), 256, 0, stream>>>(query, key, value, qb, kb, vb);
  wtrans_kernel<<<dim3(16, 16, 4), 256, 0, stream>>>(wq, wk, wv, wo, wqT, wkT, wvT, woT);
  proj_kernel<0><<<dim3(8, 32), 256, 0, stream>>>(qb, wqT, bq, Qh);
  maskpack_kernel<<<dim3(4096), 256, 0, stream>>>(mask, maskb);
  proj_kernel<0><<<dim3(8, 32), 256, 0, stream>>>(kb, wkT, bk, Kh);
  proj_kernel<1><<<dim3(8, 32), 256, 0, stream>>>(vb, wvT, bv, Vt);
  attn_pass1<<<dim3(32, 16, 2), 256, 0, stream>>>(Qh, Kh, maskb, mrow, lrow);
  attn_pass2<<<dim3(32, 16, 2), 256, 0, stream>>>(Qh, Kh, Vt, maskb, mrow, lrow, out_p, xb);
  proj_kernel<3><<<dim3(8, 32), 256, 0, stream>>>(xb, woT, bo, out_x);
}